// Round 4
// baseline (5816.792 us; speedup 1.0000x reference)
//
#include <hip/hip_runtime.h>
#include <hip/hip_bf16.h>
#include <math.h>

using bf16 = __hip_bfloat16;

#define BB 1024
#define TT 13
#define YY 188
#define HH 512
#define GG 1536
#define YP 192
#define DS 13
#define NT 96   // GG/16 B-tiles along the gate dimension

typedef __bf16 bf16x8 __attribute__((ext_vector_type(8)));
typedef float f32x4 __attribute__((ext_vector_type(4)));
typedef float f4 __attribute__((ext_vector_type(4)));

__device__ __forceinline__ float sigf(float x) { return 1.f / (1.f + expf(-x)); }
__device__ __forceinline__ bf16x8 ldf(const bf16* p) {
  return *reinterpret_cast<const bf16x8*>(p);
}
__device__ __forceinline__ f32x4 mf(bf16x8 a, bf16x8 b, f32x4 c) {
  return __builtin_amdgcn_mfma_f32_16x16x32_bf16(a, b, c, 0, 0, 0);
}
__device__ __forceinline__ void split2(float v, bf16& hi, bf16& lo) {
  hi = __float2bfloat16(v);
  lo = __float2bfloat16(v - __bfloat162float(hi));
}

// Per-phase cell table (<=13 independent (d,t) cells), passed by value.
struct GruPhase {
  int ncells;
  int zmask;             // bit c: t==0 (skip gh GEMM, h_prev = 0)
  unsigned a1off[13];    // A1 element offset per cell
  unsigned hoff[13];     // h_prev element offset per cell
  unsigned ooff[13];     // h_out  element offset per cell
};

// ---------------------------------------------------------------------------
// Swizzle a row-major (Nsrc x Ksrc) fp32 weight into KT-MAJOR MFMA B-frag
// order, split hi/lo, zero-padded. Tile (kt,nt) at elem (kt*NT + nt)*512;
// lane l holds W[nt*16+(l&15)][kt*32+(l>>4)*8+j], j=0..7 contiguous.
// NOTE (v6): this layout means a wave's B-fragment is a single coalesced
// 1 KiB global load (lane l -> 16B at +l*8 elems) -- fragment order IS the
// memory order, so B can be consumed straight from global, no LDS needed.
// ---------------------------------------------------------------------------
__global__ void k_swz2(const float* __restrict__ src, bf16* __restrict__ dhi,
                       bf16* __restrict__ dlo, int Nsrc, int Ksrc) {
  int idx = blockIdx.x * 256 + threadIdx.x;   // ((kt*NT+nt), lane)
  int l = idx & 63;
  int ktnt = idx >> 6;
  int nt = ktnt % NT, kt = ktnt / NT;
  int n = nt * 16 + (l & 15);
  int k0 = kt * 32 + (l >> 4) * 8;
#pragma unroll
  for (int j = 0; j < 8; ++j) {
    int k = k0 + j;
    float v = (n < Nsrc && k < Ksrc) ? src[(size_t)n * Ksrc + k] : 0.f;
    bf16 h, lo;
    split2(v, h, lo);
    dhi[(size_t)idx * 8 + j] = h;
    dlo[(size_t)idx * 8 + j] = lo;
  }
}

// Setup: 26-slot hi/lo token buffers (s<13: x[:,s,:]; s>=13: y_{s-13}), plus
// fp32 residual seeded with x[:,12,:].
__global__ void k_setup(const float* __restrict__ x, bf16* __restrict__ th,
                        bf16* __restrict__ tl, float* __restrict__ res) {
  int idx = blockIdx.x * 256 + threadIdx.x;
  const int total = 26 * BB * YP;
  if (idx < total) {
    int k = idx % YP;
    int b = (idx / YP) % BB;
    int s = idx / (YP * BB);
    float v = 0.f;
    if (s < TT && k < YY) v = x[((size_t)b * TT + s) * YY + k];
    bf16 h, lo;
    split2(v, h, lo);
    th[idx] = h; tl[idx] = lo;
  }
  if (idx < BB * YY) {
    int yy = idx % YY;
    int b = idx / YY;
    res[idx] = x[((size_t)b * TT + 12) * YY + yy];
  }
}

// ---------------------------------------------------------------------------
// Phase-batched GRU step v6: ZERO LDS, ZERO barriers.
// Lesson from v2-v5: with a 2-barrier-per-kt LDS structure, every scheduling
// trick (dist-1/dist-2 prefetch, global_load_lds, counted vmcnt) lands 173-
// 190us -- the structure is the ceiling, all pipes idle at ~25-30%.
// v6 removes the structure: the swizzled W layout is ALREADY fragment-order
// in global memory, so each wave loads its 12 B-frags directly (1 KiB
// coalesced per load). L1 (32KB/CU) dedupes the 4 waves' identical B reads
// -- that was LDS's only job. No shared state -> no __syncthreads at all;
// waves free-run, staggering naturally so leading waves prefetch L1/L2 for
// trailing ones. A-frags keep distance-1 register prefetch.
// Numerics: identical MFMA order -> bitwise-identical h trajectory.
// ---------------------------------------------------------------------------
template <int KT1>
__global__ __launch_bounds__(256) void gru2(
    const bf16* __restrict__ a1h, const bf16* __restrict__ a1l, int lda1,
    const bf16* __restrict__ W1h, const bf16* __restrict__ W1l,
    const float* __restrict__ b1,
    const bf16* __restrict__ hbh, const bf16* __restrict__ hbl,
    const bf16* __restrict__ W2h, const bf16* __restrict__ W2l,
    const float* __restrict__ b2,
    bf16* __restrict__ obh, bf16* __restrict__ obl,
    GruPhase ph)
{
  const int tid = threadIdx.x;
  const int w = tid >> 6, l = tid & 63;
  const int lr = l & 15, lq = l >> 4, kq = lq * 8;
  const int cell = blockIdx.y >> 3, rt = blockIdx.y & 7;
  const int cw = blockIdx.x * 32;
  const int m0 = rt * 128 + w * 32;
  const bf16* A1h = a1h + ph.a1off[cell];
  const bf16* A1l = a1l + ph.a1off[cell];
  const bf16* HPh = hbh + ph.hoff[cell];
  const bf16* HPl = hbl + ph.hoff[cell];
  bf16* HOh = obh + ph.ooff[cell];
  bf16* HOl = obl + ph.ooff[cell];
  const int zero_h = (ph.zmask >> cell) & 1;
  const int KT2 = zero_h ? 0 : 16;   // gh pass kt count (uniform per block)

  const f32x4 vzero = {0.f, 0.f, 0.f, 0.f};
  f32x4 arz[2][2][2];           // [rf][r/z][ntl] : xg+gh joint accumulation
  f32x4 axn[2][2], ahn[2][2];   // n-gate parts kept separate
#pragma unroll
  for (int rf = 0; rf < 2; ++rf)
#pragma unroll
    for (int ntl = 0; ntl < 2; ++ntl) {
      arz[rf][0][ntl] = vzero; arz[rf][1][ntl] = vzero;
      axn[rf][ntl] = vzero; ahn[rf][ntl] = vzero;
    }

  // B-fragment element offsets (without the kt term), per (g, ntl):
  // frag at ((kt*NT + ntg)*64 + l)*8, ntg = g*32 + (cw>>4) + ntl.
  size_t boff[3][2];
#pragma unroll
  for (int g = 0; g < 3; ++g)
#pragma unroll
    for (int ntl = 0; ntl < 2; ++ntl)
      boff[g][ntl] = ((size_t)(g * 32 + (cw >> 4) + ntl) * 64 + l) * 8;

  // load the 12 B-frags (3 gates x 2 ntl x hi/lo) for weight-kt ktW
  auto bload = [&](const bf16* Wh, const bf16* Wl2, int ktW,
                   bf16x8 (&bb)[3][2][2]) {
    const size_t kterm = (size_t)ktW * (NT * 512);
#pragma unroll
    for (int g = 0; g < 3; ++g)
#pragma unroll
      for (int ntl = 0; ntl < 2; ++ntl) {
        bb[g][ntl][0] = ldf(Wh + kterm + boff[g][ntl]);
        bb[g][ntl][1] = ldf(Wl2 + kterm + boff[g][ntl]);
      }
  };
  // issue A-fragment global loads (2 rf x hi/lo) for kt into regs
  auto aload = [&](const bf16* Ah, const bf16* Al, int lda, int ktA,
                   bf16x8 (&d)[2][2]) {
#pragma unroll
    for (int rf = 0; rf < 2; ++rf) {
      const size_t ao = (size_t)(m0 + rf * 16 + lr) * lda + ktA * 32 + kq;
      d[rf][0] = ldf(Ah + ao);
      d[rf][1] = ldf(Al + ao);
    }
  };
  // one kt of MFMA work, all operands in registers
  auto compute = [&](bf16x8 (&a)[2][2], bf16x8 (&bb)[3][2][2],
                     f32x4 (&an)[2][2]) {
#pragma unroll
    for (int g = 0; g < 3; ++g)
#pragma unroll
      for (int ntl = 0; ntl < 2; ++ntl) {
        bf16x8 bh  = bb[g][ntl][0];
        bf16x8 blo = bb[g][ntl][1];
#pragma unroll
        for (int rf = 0; rf < 2; ++rf) {
          if (g < 2)
            arz[rf][g][ntl] = mf(a[rf][0], blo, mf(a[rf][1], bh,
                                 mf(a[rf][0], bh, arz[rf][g][ntl])));
          else
            an[rf][ntl] = mf(a[rf][0], blo, mf(a[rf][1], bh,
                             mf(a[rf][0], bh, an[rf][ntl])));
        }
      }
  };
  auto acopy = [&](bf16x8 (&dst)[2][2], bf16x8 (&src)[2][2]) {
#pragma unroll
    for (int rf = 0; rf < 2; ++rf) {
      dst[rf][0] = src[rf][0];
      dst[rf][1] = src[rf][1];
    }
  };

  bf16x8 acur[2][2], anx[2][2], bb[3][2][2];

  // ---- prologue
  aload(A1h, A1l, lda1, 0, acur);

  // ---- pass 1: xg over KT1 kts (A = A1)
  for (int kt = 0; kt < KT1; ++kt) {
    const bool more1 = (kt + 1 < KT1);
    if (more1)     aload(A1h, A1l, lda1, kt + 1, anx);
    else if (KT2)  aload(HPh, HPl, HH, 0, anx);
    bload(W1h, W1l, kt, bb);
    compute(acur, bb, axn);
    if (more1 || KT2) acopy(acur, anx);
  }
  // ---- pass 2: gh over 16 kts (A = h_prev)
  if (KT2) {
    for (int kt = 0; kt < 16; ++kt) {
      const bool next = (kt + 1 < 16);
      if (next) aload(HPh, HPl, HH, kt + 1, anx);
      bload(W2h, W2l, kt, bb);
      compute(acur, bb, ahn);
      if (next) acopy(acur, anx);
    }
  }

  // ---- epilogue: gates + h update; h_prev = hi+lo reconstruction
#pragma unroll
  for (int ntl = 0; ntl < 2; ++ntl) {
    const int col = cw + ntl * 16 + lr;
    const float bx0 = b1[col], bx1 = b1[col + HH], bx2 = b1[col + 2 * HH];
    const float bh0 = b2[col], bh1 = b2[col + HH], bh2 = b2[col + 2 * HH];
#pragma unroll
    for (int rf = 0; rf < 2; ++rf)
#pragma unroll
      for (int i = 0; i < 4; ++i) {
        const int row = m0 + rf * 16 + lq * 4 + i;
        const float rr = sigf(arz[rf][0][ntl][i] + bx0 + bh0);
        const float zz = sigf(arz[rf][1][ntl][i] + bx1 + bh1);
        const float nn = tanhf(axn[rf][ntl][i] + bx2 + rr * (ahn[rf][ntl][i] + bh2));
        float hp = 0.f;
        const size_t hidx = (size_t)row * HH + col;
        if (!zero_h)
          hp = __bfloat162float(HPh[hidx]) + __bfloat162float(HPl[hidx]);
        const float hn = (1.f - zz) * nn + zz * hp;
        bf16 sh, sl;
        split2(hn, sh, sl);
        HOh[hidx] = sh;
        HOl[hidx] = sl;
      }
  }
}

// ---------------------------------------------------------------------------
// Output projection, last timestep only (fp32 VALU):
// o = relu(h1) @ W_out^T + b_out + res; res <- o; d_out[:,d,:] <- o (fp32);
// token slot 13+d <- split-bf16(o).  h1 comes in as hi/lo bf16.
// ---------------------------------------------------------------------------
__global__ __launch_bounds__(256) void out_v(
    const bf16* __restrict__ h1h, const bf16* __restrict__ h1l,
    const float* __restrict__ Wo,
    const float* __restrict__ bo,
    float* __restrict__ res,
    bf16* __restrict__ yh, bf16* __restrict__ yl,
    float* __restrict__ outp,
    int d)
{
  int idx = blockIdx.x * 256 + threadIdx.x;
  if (idx >= BB * YY) return;
  int col = idx % YY, row = idx / YY;
  const bf16* hrh = h1h + (size_t)row * HH;
  const bf16* hrl = h1l + (size_t)row * HH;
  const float* wr = Wo + (size_t)col * HH;
  float acc = 0.f;
#pragma unroll 2
  for (int k = 0; k < HH; k += 8) {
    bf16x8 hh = ldf(hrh + k);
    bf16x8 hl = ldf(hrl + k);
    f4 w0 = *(const f4*)&wr[k];
    f4 w1 = *(const f4*)&wr[k + 4];
#pragma unroll
    for (int j = 0; j < 4; ++j) {
      float hv0 = (float)hh[j] + (float)hl[j];
      float hv1 = (float)hh[j + 4] + (float)hl[j + 4];
      acc = fmaf(fmaxf(hv0, 0.f), w0[j], acc);
      acc = fmaf(fmaxf(hv1, 0.f), w1[j], acc);
    }
  }
  float o = acc + bo[col] + res[idx];
  res[idx] = o;
  outp[((size_t)row * DS + d) * YY + col] = o;
  bf16 sh, sl;
  split2(o, sh, sl);
  yh[(size_t)row * YP + col] = sh;
  yl[(size_t)row * YP + col] = sl;
}

extern "C" void kernel_launch(void* const* d_in, const int* in_sizes, int n_in,
                              void* d_out, int out_size, void* d_ws, size_t ws_size,
                              hipStream_t stream)
{
  // role mapping insurance (dict-order signature, greedy fallback)
  static const int sig_dict[11] = {2501632, 288768, 786432, 1536, 1536,
                                   786432, 786432, 1536, 1536, 96256, 188};
  int map[11];
  bool dict_ok = (n_in == 11);
  if (dict_ok)
    for (int r = 0; r < 11; ++r)
      if (in_sizes[r] != sig_dict[r]) { dict_ok = false; break; }
  if (dict_ok) { for (int r = 0; r < 11; ++r) map[r] = r; }
  else {
    bool used[16] = {};
    for (int r = 0; r < 11; ++r) {
      map[r] = r < n_in ? r : 0;
      for (int i = 0; i < n_in && i < 16; ++i)
        if (!used[i] && in_sizes[i] == sig_dict[r]) { map[r] = i; used[i] = true; break; }
    }
  }
  const float* x     = (const float*)d_in[map[0]];
  const float* W_ih0 = (const float*)d_in[map[1]];
  const float* W_hh0 = (const float*)d_in[map[2]];
  const float* b_ih0 = (const float*)d_in[map[3]];
  const float* b_hh0 = (const float*)d_in[map[4]];
  const float* W_ih1 = (const float*)d_in[map[5]];
  const float* W_hh1 = (const float*)d_in[map[6]];
  const float* b_ih1 = (const float*)d_in[map[7]];
  const float* b_hh1 = (const float*)d_in[map[8]];
  const float* W_out = (const float*)d_in[map[9]];
  const float* b_out = (const float*)d_in[map[10]];
  float* outp = (float*)d_out;

  // Schedule selection: skew-1 (25 phases, 13 h-slots, ~136 MB) if workspace
  // allows, else the proven skew-2 (37 phases, 7 slots, ~88 MB). ws_size is
  // fixed per-harness, so every call takes the same path (graph-safe).
  const int S    = (ws_size >= (size_t)160 << 20) ? 13 : 7;
  const int SKEW = (S == 13) ? 1 : 2;
  const int NPH  = 12 * SKEW + 13;

  char* p = (char*)d_ws;
  auto alloc = [&](size_t bytes) { char* q = p; p += (bytes + 255) & ~(size_t)255; return q; };
  bf16* tokh = (bf16*)alloc((size_t)26 * BB * YP * 2);
  bf16* tokl = (bf16*)alloc((size_t)26 * BB * YP * 2);
  bf16* W0h  = (bf16*)alloc((size_t)GG * YP * 2);
  bf16* W0l  = (bf16*)alloc((size_t)GG * YP * 2);
  bf16* Wh0h = (bf16*)alloc((size_t)GG * HH * 2);
  bf16* Wh0l = (bf16*)alloc((size_t)GG * HH * 2);
  bf16* Wi1h = (bf16*)alloc((size_t)GG * HH * 2);
  bf16* Wi1l = (bf16*)alloc((size_t)GG * HH * 2);
  bf16* Wh1h = (bf16*)alloc((size_t)GG * HH * 2);
  bf16* Wh1l = (bf16*)alloc((size_t)GG * HH * 2);
  bf16* h0h = (bf16*)alloc((size_t)2 * S * BB * HH * 2);  // parity x slot
  bf16* h0l = (bf16*)alloc((size_t)2 * S * BB * HH * 2);
  bf16* h1h = (bf16*)alloc((size_t)2 * S * BB * HH * 2);
  bf16* h1l = (bf16*)alloc((size_t)2 * S * BB * HH * 2);
  float* res = (float*)alloc((size_t)BB * YY * 4);

  k_setup<<<(26 * BB * YP + 255) / 256, 256, 0, stream>>>(x, tokh, tokl, res);
  k_swz2<<<NT * (YP / 32) * 64 / 256, 256, 0, stream>>>(W_ih0, W0h, W0l, GG, YY);
  k_swz2<<<NT * (HH / 32) * 64 / 256, 256, 0, stream>>>(W_hh0, Wh0h, Wh0l, GG, HH);
  k_swz2<<<NT * (HH / 32) * 64 / 256, 256, 0, stream>>>(W_ih1, Wi1h, Wi1l, GG, HH);
  k_swz2<<<NT * (HH / 32) * 64 / 256, 256, 0, stream>>>(W_hh1, Wh1h, Wh1l, GG, HH);

  // Diagonal wavefront: phase(d,t) = t + SKEW*d. Cells in phase p read
  // h-parity (p-1)&1, write p&1; slot = d % S.
  for (int phs = 0; phs < NPH; ++phs) {
    GruPhase P0{}, P1{};
    const int pprev = (phs + 1) & 1, pcur = phs & 1;
    int C = 0;
    for (int d = 0; d < DS; ++d) {
      int t = phs - SKEW * d;
      if (t < 0 || t > 12) continue;
      int c = C++;
      P0.a1off[c] = (unsigned)((d + t) * BB * YP);          // token slot d+t
      P0.hoff[c]  = (unsigned)((pprev * S + d % S) * BB * HH);
      P0.ooff[c]  = (unsigned)((pcur * S + d % S) * BB * HH);
      if (t == 0) P0.zmask |= 1 << c;
      P1.a1off[c] = P0.ooff[c];   // L1 input = L0 output of this phase
      P1.hoff[c]  = P0.hoff[c];
      P1.ooff[c]  = P0.ooff[c];
    }
    P0.ncells = P1.ncells = C;
    P1.zmask = P0.zmask;
    const dim3 grid(16, C * 8);   // x=colgroups (XCD locality), y=row-tiles
    gru2<YP / 32><<<grid, 256, 0, stream>>>(tokh, tokl, YP, W0h, W0l, b_ih0,
                                            h0h, h0l, Wh0h, Wh0l, b_hh0,
                                            h0h, h0l, P0);
    gru2<HH / 32><<<grid, 256, 0, stream>>>(h0h, h0l, HH, Wi1h, Wi1l, b_ih1,
                                            h1h, h1l, Wh1h, Wh1l, b_hh1,
                                            h1h, h1l, P1);
    // decode step d finishes at phase 12 + SKEW*d: project + feed token 13+d
    if (phs >= 12 && (phs - 12) % SKEW == 0) {
      const int d = (phs - 12) / SKEW;
      const size_t hoff = (size_t)(pcur * S + d % S) * BB * HH;
      out_v<<<(BB * YY + 255) / 256, 256, 0, stream>>>(
          h1h + hoff, h1l + hoff, W_out, b_out, res,
          tokh + (size_t)(13 + d) * BB * YP, tokl + (size_t)(13 + d) * BB * YP,
          outp, d);
    }
  }
}

// Round 5
// 4583.968 us; speedup vs baseline: 1.2689x; 1.2689x over previous
//
#include <hip/hip_runtime.h>
#include <hip/hip_bf16.h>
#include <math.h>

using bf16 = __hip_bfloat16;

#define BB 1024
#define TT 13
#define YY 188
#define HH 512
#define GG 1536
#define YP 192
#define DS 13
#define NT 96   // GG/16 B-tiles along the gate dimension

typedef __bf16 bf16x8 __attribute__((ext_vector_type(8)));
typedef float f32x4 __attribute__((ext_vector_type(4)));
typedef float f4 __attribute__((ext_vector_type(4)));

__device__ __forceinline__ float sigf(float x) { return 1.f / (1.f + expf(-x)); }
__device__ __forceinline__ bf16x8 ldf(const bf16* p) {
  return *reinterpret_cast<const bf16x8*>(p);
}
__device__ __forceinline__ f32x4 mf(bf16x8 a, bf16x8 b, f32x4 c) {
  return __builtin_amdgcn_mfma_f32_16x16x32_bf16(a, b, c, 0, 0, 0);
}
__device__ __forceinline__ void split2(float v, bf16& hi, bf16& lo) {
  hi = __float2bfloat16(v);
  lo = __float2bfloat16(v - __bfloat162float(hi));
}

// Per-phase cell table (<=13 independent (d,t) cells), passed by value.
struct GruPhase {
  int ncells;
  int zmask;             // bit c: t==0 (skip gh GEMM, h_prev = 0)
  unsigned a1off[13];    // A1 element offset per cell
  unsigned hoff[13];     // h_prev element offset per cell
  unsigned ooff[13];     // h_out  element offset per cell
};

// ---------------------------------------------------------------------------
// Swizzle a row-major (Nsrc x Ksrc) fp32 weight into KT-MAJOR MFMA B-frag
// order, split hi/lo, zero-padded. Tile (kt,nt) at elem (kt*NT + nt)*512;
// lane l holds W[nt*16+(l&15)][kt*32+(l>>4)*8+j], j=0..7 contiguous.
// ---------------------------------------------------------------------------
__global__ void k_swz2(const float* __restrict__ src, bf16* __restrict__ dhi,
                       bf16* __restrict__ dlo, int Nsrc, int Ksrc) {
  int idx = blockIdx.x * 256 + threadIdx.x;   // ((kt*NT+nt), lane)
  int l = idx & 63;
  int ktnt = idx >> 6;
  int nt = ktnt % NT, kt = ktnt / NT;
  int n = nt * 16 + (l & 15);
  int k0 = kt * 32 + (l >> 4) * 8;
#pragma unroll
  for (int j = 0; j < 8; ++j) {
    int k = k0 + j;
    float v = (n < Nsrc && k < Ksrc) ? src[(size_t)n * Ksrc + k] : 0.f;
    bf16 h, lo;
    split2(v, h, lo);
    dhi[(size_t)idx * 8 + j] = h;
    dlo[(size_t)idx * 8 + j] = lo;
  }
}

// Setup: 26-slot hi/lo token buffers (s<13: x[:,s,:]; s>=13: y_{s-13}), plus
// fp32 residual seeded with x[:,12,:].
__global__ void k_setup(const float* __restrict__ x, bf16* __restrict__ th,
                        bf16* __restrict__ tl, float* __restrict__ res) {
  int idx = blockIdx.x * 256 + threadIdx.x;
  const int total = 26 * BB * YP;
  if (idx < total) {
    int k = idx % YP;
    int b = (idx / YP) % BB;
    int s = idx / (YP * BB);
    float v = 0.f;
    if (s < TT && k < YY) v = x[((size_t)b * TT + s) * YY + k];
    bf16 h, lo;
    split2(v, h, lo);
    th[idx] = h; tl[idx] = lo;
  }
  if (idx < BB * YY) {
    int yy = idx % YY;
    int b = idx / YY;
    res[idx] = x[((size_t)b * TT + 12) * YY + yy];
  }
}

// ---------------------------------------------------------------------------
// Phase-batched GRU step v7: 128x64 block tile (VMEM-bytes-per-MFMA cut).
// Diagnosis across v3-v6: the kernel is VMEM/L1-pipe-bound (~28 KB per
// block-kt through the TA path for 144 MFMA = 0.194 KB/MFMA; v6's 64 KB
// variant scaled time with bytes, scheduling variants v4/v5 with equal
// bytes were neutral/worse). Fix = fewer bytes per MFMA, not scheduling:
// widen the column tile 32 -> 64. Per block-kt: A 16 KB (unchanged),
// W 24 KB, MFMA 288 -> 0.139 KB/MFMA (-28%); chip-total A re-reads halve
// (8 colgroups, one per XCD). Same proven v3 loop structure (reg-staged W,
// dist-1 A prefetch, one full-drain barrier per kt).
// Numerics: identical per-element MFMA order -> bitwise-identical.
// ---------------------------------------------------------------------------
template <int KT1>
__global__ __launch_bounds__(256, 2) void gru2(
    const bf16* __restrict__ a1h, const bf16* __restrict__ a1l, int lda1,
    const bf16* __restrict__ W1h, const bf16* __restrict__ W1l,
    const float* __restrict__ b1,
    const bf16* __restrict__ hbh, const bf16* __restrict__ hbl,
    const bf16* __restrict__ W2h, const bf16* __restrict__ W2l,
    const float* __restrict__ b2,
    bf16* __restrict__ obh, bf16* __restrict__ obl,
    GruPhase ph)
{
  __shared__ __align__(16) __bf16 Bl[2][24][512];
  const int tid = threadIdx.x;
  const int w = tid >> 6, l = tid & 63;
  const int lr = l & 15, lq = l >> 4, kq = lq * 8;
  const int cell = blockIdx.y >> 3, rt = blockIdx.y & 7;
  const int cw = blockIdx.x * 64;        // 64-col groups, one per XCD
  const int m0 = rt * 128 + w * 32;
  const bf16* A1h = a1h + ph.a1off[cell];
  const bf16* A1l = a1l + ph.a1off[cell];
  const bf16* HPh = hbh + ph.hoff[cell];
  const bf16* HPl = hbl + ph.hoff[cell];
  bf16* HOh = obh + ph.ooff[cell];
  bf16* HOl = obl + ph.ooff[cell];
  const int zero_h = (ph.zmask >> cell) & 1;
  const int KT2 = zero_h ? 0 : 16;   // gh pass kt count (uniform per block)

  const f32x4 vzero = {0.f, 0.f, 0.f, 0.f};
  f32x4 arz[2][2][4];           // [rf][r/z][ntl] : xg+gh joint accumulation
  f32x4 axn[2][4], ahn[2][4];   // n-gate parts kept separate
#pragma unroll
  for (int rf = 0; rf < 2; ++rf)
#pragma unroll
    for (int ntl = 0; ntl < 4; ++ntl) {
      arz[rf][0][ntl] = vzero; arz[rf][1][ntl] = vzero;
      axn[rf][ntl] = vzero; ahn[rf][ntl] = vzero;
    }

  // Staging geometry: 24 KiB/kt = 1536 16B-units; 6 per thread.
  // u = r*256 + tid -> tile tl2 = r*4 + w (wave-uniform), unit = lane l.
  // tl2 = (g*4+ntl)*2 + hl; ntg = g*32 + bx*4 + ntl.
  int tl2a[6], hlr[6];
  size_t soff[6];
#pragma unroll
  for (int r = 0; r < 6; ++r) {
    const int tl2 = r * 4 + w;
    const int hl = tl2 & 1;
    const int gn = tl2 >> 1;            // 0..11
    const int g = gn >> 2, ntl = gn & 3;
    const int ntg = g * 32 + (cw >> 4) + ntl;
    tl2a[r] = tl2; hlr[r] = hl;
    soff[r] = ((size_t)ntg * 64 + l) * 8;
  }

  // issue the 24 KiB B-slice global loads for weight-kt ktW into regs
  auto stage_load = [&](const bf16* Wh, const bf16* Wl2, int ktW,
                        bf16x8 (&v)[6]) {
#pragma unroll
    for (int r = 0; r < 6; ++r)
      v[r] = ldf((hlr[r] ? Wl2 : Wh) + soff[r] + (size_t)ktW * (NT * 512));
  };
  // commit staged regs to LDS buffer `buf` (vmcnt wait lands here, post-MFMA)
  auto stage_write = [&](bf16x8 (&v)[6], int buf) {
#pragma unroll
    for (int r = 0; r < 6; ++r)
      *(bf16x8*)(&Bl[buf][tl2a[r]][l * 8]) = v[r];
  };
  // issue A-fragment global loads (2 rf x hi/lo) for kt into regs
  auto aload = [&](const bf16* Ah, const bf16* Al, int lda, int ktA,
                   bf16x8 (&d)[2][2]) {
#pragma unroll
    for (int rf = 0; rf < 2; ++rf) {
      const size_t ao = (size_t)(m0 + rf * 16 + lr) * lda + ktA * 32 + kq;
      d[rf][0] = ldf(Ah + ao);
      d[rf][1] = ldf(Al + ao);
    }
  };
  // one kt of MFMA work from pre-loaded A regs + LDS buffer `buf`
  auto compute = [&](bf16x8 (&a)[2][2], int buf, f32x4 (&an)[2][4]) {
#pragma unroll
    for (int g = 0; g < 3; ++g)
#pragma unroll
      for (int ntl = 0; ntl < 4; ++ntl) {
        int tl2 = (g * 4 + ntl) * 2;
        bf16x8 bh  = *(const bf16x8*)(&Bl[buf][tl2][l * 8]);
        bf16x8 blo = *(const bf16x8*)(&Bl[buf][tl2 + 1][l * 8]);
#pragma unroll
        for (int rf = 0; rf < 2; ++rf) {
          if (g < 2)
            arz[rf][g][ntl] = mf(a[rf][0], blo, mf(a[rf][1], bh,
                                 mf(a[rf][0], bh, arz[rf][g][ntl])));
          else
            an[rf][ntl] = mf(a[rf][0], blo, mf(a[rf][1], bh,
                             mf(a[rf][0], bh, an[rf][ntl])));
        }
      }
  };
  auto acopy = [&](bf16x8 (&dst)[2][2], bf16x8 (&src)[2][2]) {
#pragma unroll
    for (int rf = 0; rf < 2; ++rf) {
      dst[rf][0] = src[rf][0];
      dst[rf][1] = src[rf][1];
    }
  };

  bf16x8 w0[6], w1[6], acur[2][2], anx[2][2];

  // ---- prologue: tile 0 of pass 1
  stage_load(W1h, W1l, 0, w0);
  aload(A1h, A1l, lda1, 0, acur);
  stage_write(w0, 0);
  __syncthreads();

  // ---- pass 1: xg over KT1 kts (A = A1)
  for (int kt = 0; kt < KT1; ++kt) {
    const int buf = kt & 1;
    const bool more1 = (kt + 1 < KT1);
    const bool next = more1 || (KT2 > 0);
    if (more1)      { stage_load(W1h, W1l, kt + 1, w1); aload(A1h, A1l, lda1, kt + 1, anx); }
    else if (KT2)   { stage_load(W2h, W2l, 0, w1);      aload(HPh, HPl, HH, 0, anx); }
    compute(acur, buf, axn);
    if (next) stage_write(w1, buf ^ 1);
    __syncthreads();
    if (next) acopy(acur, anx);
  }
  // ---- pass 2: gh over 16 kts (A = h_prev)
  if (KT2) {
    for (int kt = 0; kt < 16; ++kt) {
      const int buf = (KT1 + kt) & 1;
      const bool next = (kt + 1 < 16);
      if (next) { stage_load(W2h, W2l, kt + 1, w1); aload(HPh, HPl, HH, kt + 1, anx); }
      compute(acur, buf, ahn);
      if (next) stage_write(w1, buf ^ 1);
      __syncthreads();
      if (next) acopy(acur, anx);
    }
  }

  // ---- epilogue: gates + h update; h_prev = hi+lo reconstruction
#pragma unroll
  for (int ntl = 0; ntl < 4; ++ntl) {
    const int col = cw + ntl * 16 + lr;
    const float bx0 = b1[col], bx1 = b1[col + HH], bx2 = b1[col + 2 * HH];
    const float bh0 = b2[col], bh1 = b2[col + HH], bh2 = b2[col + 2 * HH];
#pragma unroll
    for (int rf = 0; rf < 2; ++rf)
#pragma unroll
      for (int i = 0; i < 4; ++i) {
        const int row = m0 + rf * 16 + lq * 4 + i;
        const float rr = sigf(arz[rf][0][ntl][i] + bx0 + bh0);
        const float zz = sigf(arz[rf][1][ntl][i] + bx1 + bh1);
        const float nn = tanhf(axn[rf][ntl][i] + bx2 + rr * (ahn[rf][ntl][i] + bh2));
        float hp = 0.f;
        const size_t hidx = (size_t)row * HH + col;
        if (!zero_h)
          hp = __bfloat162float(HPh[hidx]) + __bfloat162float(HPl[hidx]);
        const float hn = (1.f - zz) * nn + zz * hp;
        bf16 sh, sl;
        split2(hn, sh, sl);
        HOh[hidx] = sh;
        HOl[hidx] = sl;
      }
  }
}

// ---------------------------------------------------------------------------
// Output projection, last timestep only (fp32 VALU):
// o = relu(h1) @ W_out^T + b_out + res; res <- o; d_out[:,d,:] <- o (fp32);
// token slot 13+d <- split-bf16(o).  h1 comes in as hi/lo bf16.
// ---------------------------------------------------------------------------
__global__ __launch_bounds__(256) void out_v(
    const bf16* __restrict__ h1h, const bf16* __restrict__ h1l,
    const float* __restrict__ Wo,
    const float* __restrict__ bo,
    float* __restrict__ res,
    bf16* __restrict__ yh, bf16* __restrict__ yl,
    float* __restrict__ outp,
    int d)
{
  int idx = blockIdx.x * 256 + threadIdx.x;
  if (idx >= BB * YY) return;
  int col = idx % YY, row = idx / YY;
  const bf16* hrh = h1h + (size_t)row * HH;
  const bf16* hrl = h1l + (size_t)row * HH;
  const float* wr = Wo + (size_t)col * HH;
  float acc = 0.f;
#pragma unroll 2
  for (int k = 0; k < HH; k += 8) {
    bf16x8 hh = ldf(hrh + k);
    bf16x8 hl = ldf(hrl + k);
    f4 w0 = *(const f4*)&wr[k];
    f4 w1 = *(const f4*)&wr[k + 4];
#pragma unroll
    for (int j = 0; j < 4; ++j) {
      float hv0 = (float)hh[j] + (float)hl[j];
      float hv1 = (float)hh[j + 4] + (float)hl[j + 4];
      acc = fmaf(fmaxf(hv0, 0.f), w0[j], acc);
      acc = fmaf(fmaxf(hv1, 0.f), w1[j], acc);
    }
  }
  float o = acc + bo[col] + res[idx];
  res[idx] = o;
  outp[((size_t)row * DS + d) * YY + col] = o;
  bf16 sh, sl;
  split2(o, sh, sl);
  yh[(size_t)row * YP + col] = sh;
  yl[(size_t)row * YP + col] = sl;
}

extern "C" void kernel_launch(void* const* d_in, const int* in_sizes, int n_in,
                              void* d_out, int out_size, void* d_ws, size_t ws_size,
                              hipStream_t stream)
{
  // role mapping insurance (dict-order signature, greedy fallback)
  static const int sig_dict[11] = {2501632, 288768, 786432, 1536, 1536,
                                   786432, 786432, 1536, 1536, 96256, 188};
  int map[11];
  bool dict_ok = (n_in == 11);
  if (dict_ok)
    for (int r = 0; r < 11; ++r)
      if (in_sizes[r] != sig_dict[r]) { dict_ok = false; break; }
  if (dict_ok) { for (int r = 0; r < 11; ++r) map[r] = r; }
  else {
    bool used[16] = {};
    for (int r = 0; r < 11; ++r) {
      map[r] = r < n_in ? r : 0;
      for (int i = 0; i < n_in && i < 16; ++i)
        if (!used[i] && in_sizes[i] == sig_dict[r]) { map[r] = i; used[i] = true; break; }
    }
  }
  const float* x     = (const float*)d_in[map[0]];
  const float* W_ih0 = (const float*)d_in[map[1]];
  const float* W_hh0 = (const float*)d_in[map[2]];
  const float* b_ih0 = (const float*)d_in[map[3]];
  const float* b_hh0 = (const float*)d_in[map[4]];
  const float* W_ih1 = (const float*)d_in[map[5]];
  const float* W_hh1 = (const float*)d_in[map[6]];
  const float* b_ih1 = (const float*)d_in[map[7]];
  const float* b_hh1 = (const float*)d_in[map[8]];
  const float* W_out = (const float*)d_in[map[9]];
  const float* b_out = (const float*)d_in[map[10]];
  float* outp = (float*)d_out;

  // Schedule selection: skew-1 (25 phases, 13 h-slots, ~136 MB) if workspace
  // allows, else the proven skew-2 (37 phases, 7 slots, ~88 MB). ws_size is
  // fixed per-harness, so every call takes the same path (graph-safe).
  const int S    = (ws_size >= (size_t)160 << 20) ? 13 : 7;
  const int SKEW = (S == 13) ? 1 : 2;
  const int NPH  = 12 * SKEW + 13;

  char* p = (char*)d_ws;
  auto alloc = [&](size_t bytes) { char* q = p; p += (bytes + 255) & ~(size_t)255; return q; };
  bf16* tokh = (bf16*)alloc((size_t)26 * BB * YP * 2);
  bf16* tokl = (bf16*)alloc((size_t)26 * BB * YP * 2);
  bf16* W0h  = (bf16*)alloc((size_t)GG * YP * 2);
  bf16* W0l  = (bf16*)alloc((size_t)GG * YP * 2);
  bf16* Wh0h = (bf16*)alloc((size_t)GG * HH * 2);
  bf16* Wh0l = (bf16*)alloc((size_t)GG * HH * 2);
  bf16* Wi1h = (bf16*)alloc((size_t)GG * HH * 2);
  bf16* Wi1l = (bf16*)alloc((size_t)GG * HH * 2);
  bf16* Wh1h = (bf16*)alloc((size_t)GG * HH * 2);
  bf16* Wh1l = (bf16*)alloc((size_t)GG * HH * 2);
  bf16* h0h = (bf16*)alloc((size_t)2 * S * BB * HH * 2);  // parity x slot
  bf16* h0l = (bf16*)alloc((size_t)2 * S * BB * HH * 2);
  bf16* h1h = (bf16*)alloc((size_t)2 * S * BB * HH * 2);
  bf16* h1l = (bf16*)alloc((size_t)2 * S * BB * HH * 2);
  float* res = (float*)alloc((size_t)BB * YY * 4);

  k_setup<<<(26 * BB * YP + 255) / 256, 256, 0, stream>>>(x, tokh, tokl, res);
  k_swz2<<<NT * (YP / 32) * 64 / 256, 256, 0, stream>>>(W_ih0, W0h, W0l, GG, YY);
  k_swz2<<<NT * (HH / 32) * 64 / 256, 256, 0, stream>>>(W_hh0, Wh0h, Wh0l, GG, HH);
  k_swz2<<<NT * (HH / 32) * 64 / 256, 256, 0, stream>>>(W_ih1, Wi1h, Wi1l, GG, HH);
  k_swz2<<<NT * (HH / 32) * 64 / 256, 256, 0, stream>>>(W_hh1, Wh1h, Wh1l, GG, HH);

  // Diagonal wavefront: phase(d,t) = t + SKEW*d. Cells in phase p read
  // h-parity (p-1)&1, write p&1; slot = d % S.
  for (int phs = 0; phs < NPH; ++phs) {
    GruPhase P0{}, P1{};
    const int pprev = (phs + 1) & 1, pcur = phs & 1;
    int C = 0;
    for (int d = 0; d < DS; ++d) {
      int t = phs - SKEW * d;
      if (t < 0 || t > 12) continue;
      int c = C++;
      P0.a1off[c] = (unsigned)((d + t) * BB * YP);          // token slot d+t
      P0.hoff[c]  = (unsigned)((pprev * S + d % S) * BB * HH);
      P0.ooff[c]  = (unsigned)((pcur * S + d % S) * BB * HH);
      if (t == 0) P0.zmask |= 1 << c;
      P1.a1off[c] = P0.ooff[c];   // L1 input = L0 output of this phase
      P1.hoff[c]  = P0.hoff[c];
      P1.ooff[c]  = P0.ooff[c];
    }
    P0.ncells = P1.ncells = C;
    P1.zmask = P0.zmask;
    const dim3 grid(8, C * 8);    // x=8 colgroups (one per XCD), y=row-tiles
    gru2<YP / 32><<<grid, 256, 0, stream>>>(tokh, tokl, YP, W0h, W0l, b_ih0,
                                            h0h, h0l, Wh0h, Wh0l, b_hh0,
                                            h0h, h0l, P0);
    gru2<HH / 32><<<grid, 256, 0, stream>>>(h0h, h0l, HH, Wi1h, Wi1l, b_ih1,
                                            h1h, h1l, Wh1h, Wh1l, b_hh1,
                                            h1h, h1l, P1);
    // decode step d finishes at phase 12 + SKEW*d: project + feed token 13+d
    if (phs >= 12 && (phs - 12) % SKEW == 0) {
      const int d = (phs - 12) / SKEW;
      const size_t hoff = (size_t)(pcur * S + d % S) * BB * HH;
      out_v<<<(BB * YY + 255) / 256, 256, 0, stream>>>(
          h1h + hoff, h1l + hoff, W_out, b_out, res,
          tokh + (size_t)(13 + d) * BB * YP, tokl + (size_t)(13 + d) * BB * YP,
          outp, d);
    }
  }
}

// Round 6
// 4207.497 us; speedup vs baseline: 1.3825x; 1.0895x over previous
//
#include <hip/hip_runtime.h>
#include <hip/hip_bf16.h>
#include <math.h>

using bf16 = __hip_bfloat16;

#define BB 1024
#define TT 13
#define YY 188
#define HH 512
#define GG 1536
#define YP 192
#define DS 13
#define NT 96    // GG/16 B-tiles along the gate dimension
#define NTO 12   // YP/16 B-tiles for the output projection

typedef __bf16 bf16x8 __attribute__((ext_vector_type(8)));
typedef float f32x4 __attribute__((ext_vector_type(4)));
typedef float f4 __attribute__((ext_vector_type(4)));

__device__ __forceinline__ float sigf(float x) { return 1.f / (1.f + expf(-x)); }
__device__ __forceinline__ bf16x8 ldf(const bf16* p) {
  return *reinterpret_cast<const bf16x8*>(p);
}
__device__ __forceinline__ f32x4 mf(bf16x8 a, bf16x8 b, f32x4 c) {
  return __builtin_amdgcn_mfma_f32_16x16x32_bf16(a, b, c, 0, 0, 0);
}
__device__ __forceinline__ void split2(float v, bf16& hi, bf16& lo) {
  hi = __float2bfloat16(v);
  lo = __float2bfloat16(v - __bfloat162float(hi));
}

// Per-phase cell table (<=13 independent (d,t) cells), passed by value.
struct GruPhase {
  int ncells;
  int zmask;             // bit c: t==0 (skip gh GEMM, h_prev = 0)
  unsigned a1off[13];    // A1 element offset per cell
  unsigned hoff[13];     // h_prev element offset per cell
  unsigned ooff[13];     // h_out  element offset per cell
};

// ---------------------------------------------------------------------------
// Swizzle a row-major (Nsrc x Ksrc) fp32 weight into KT-MAJOR MFMA B-frag
// order, split hi/lo, zero-padded. Tile (kt,nt) at elem (kt*ntiles + nt)*512;
// lane l holds W[nt*16+(l&15)][kt*32+(l>>4)*8+j], j=0..7 contiguous.
// ---------------------------------------------------------------------------
__global__ void k_swz2(const float* __restrict__ src, bf16* __restrict__ dhi,
                       bf16* __restrict__ dlo, int Nsrc, int Ksrc, int ntiles) {
  int idx = blockIdx.x * 256 + threadIdx.x;   // ((kt*ntiles+nt), lane)
  int l = idx & 63;
  int ktnt = idx >> 6;
  int nt = ktnt % ntiles, kt = ktnt / ntiles;
  int n = nt * 16 + (l & 15);
  int k0 = kt * 32 + (l >> 4) * 8;
#pragma unroll
  for (int j = 0; j < 8; ++j) {
    int k = k0 + j;
    float v = (n < Nsrc && k < Ksrc) ? src[(size_t)n * Ksrc + k] : 0.f;
    bf16 h, lo;
    split2(v, h, lo);
    dhi[(size_t)idx * 8 + j] = h;
    dlo[(size_t)idx * 8 + j] = lo;
  }
}

// Setup: 26-slot hi/lo token buffers (s<13: x[:,s,:]; s>=13: y_{s-13}), plus
// fp32 residual seeded with x[:,12,:].
__global__ void k_setup(const float* __restrict__ x, bf16* __restrict__ th,
                        bf16* __restrict__ tl, float* __restrict__ res) {
  int idx = blockIdx.x * 256 + threadIdx.x;
  const int total = 26 * BB * YP;
  if (idx < total) {
    int k = idx % YP;
    int b = (idx / YP) % BB;
    int s = idx / (YP * BB);
    float v = 0.f;
    if (s < TT && k < YY) v = x[((size_t)b * TT + s) * YY + k];
    bf16 h, lo;
    split2(v, h, lo);
    th[idx] = h; tl[idx] = lo;
  }
  if (idx < BB * YY) {
    int yy = idx % YY;
    int b = idx / YY;
    res[idx] = x[((size_t)b * TT + 12) * YY + yy];
  }
}

// ---------------------------------------------------------------------------
// Phase-batched GRU step v7 (big-C path): 128x64 block tile. Confirmed by R5
// counters (136us @C=13, MfmaUtil 37.6) -- UNCHANGED this round (control).
// ---------------------------------------------------------------------------
template <int KT1>
__global__ __launch_bounds__(256, 2) void gru2(
    const bf16* __restrict__ a1h, const bf16* __restrict__ a1l, int lda1,
    const bf16* __restrict__ W1h, const bf16* __restrict__ W1l,
    const float* __restrict__ b1,
    const bf16* __restrict__ hbh, const bf16* __restrict__ hbl,
    const bf16* __restrict__ W2h, const bf16* __restrict__ W2l,
    const float* __restrict__ b2,
    bf16* __restrict__ obh, bf16* __restrict__ obl,
    GruPhase ph)
{
  __shared__ __align__(16) __bf16 Bl[2][24][512];
  const int tid = threadIdx.x;
  const int w = tid >> 6, l = tid & 63;
  const int lr = l & 15, lq = l >> 4, kq = lq * 8;
  const int cell = blockIdx.y >> 3, rt = blockIdx.y & 7;
  const int cw = blockIdx.x * 64;        // 64-col groups, one per XCD
  const int m0 = rt * 128 + w * 32;
  const bf16* A1h = a1h + ph.a1off[cell];
  const bf16* A1l = a1l + ph.a1off[cell];
  const bf16* HPh = hbh + ph.hoff[cell];
  const bf16* HPl = hbl + ph.hoff[cell];
  bf16* HOh = obh + ph.ooff[cell];
  bf16* HOl = obl + ph.ooff[cell];
  const int zero_h = (ph.zmask >> cell) & 1;
  const int KT2 = zero_h ? 0 : 16;   // gh pass kt count (uniform per block)

  const f32x4 vzero = {0.f, 0.f, 0.f, 0.f};
  f32x4 arz[2][2][4];           // [rf][r/z][ntl] : xg+gh joint accumulation
  f32x4 axn[2][4], ahn[2][4];   // n-gate parts kept separate
#pragma unroll
  for (int rf = 0; rf < 2; ++rf)
#pragma unroll
    for (int ntl = 0; ntl < 4; ++ntl) {
      arz[rf][0][ntl] = vzero; arz[rf][1][ntl] = vzero;
      axn[rf][ntl] = vzero; ahn[rf][ntl] = vzero;
    }

  // Staging geometry: 24 KiB/kt = 1536 16B-units; 6 per thread.
  int tl2a[6], hlr[6];
  size_t soff[6];
#pragma unroll
  for (int r = 0; r < 6; ++r) {
    const int tl2 = r * 4 + w;
    const int hl = tl2 & 1;
    const int gn = tl2 >> 1;            // 0..11
    const int g = gn >> 2, ntl = gn & 3;
    const int ntg = g * 32 + (cw >> 4) + ntl;
    tl2a[r] = tl2; hlr[r] = hl;
    soff[r] = ((size_t)ntg * 64 + l) * 8;
  }

  auto stage_load = [&](const bf16* Wh, const bf16* Wl2, int ktW,
                        bf16x8 (&v)[6]) {
#pragma unroll
    for (int r = 0; r < 6; ++r)
      v[r] = ldf((hlr[r] ? Wl2 : Wh) + soff[r] + (size_t)ktW * (NT * 512));
  };
  auto stage_write = [&](bf16x8 (&v)[6], int buf) {
#pragma unroll
    for (int r = 0; r < 6; ++r)
      *(bf16x8*)(&Bl[buf][tl2a[r]][l * 8]) = v[r];
  };
  auto aload = [&](const bf16* Ah, const bf16* Al, int lda, int ktA,
                   bf16x8 (&d)[2][2]) {
#pragma unroll
    for (int rf = 0; rf < 2; ++rf) {
      const size_t ao = (size_t)(m0 + rf * 16 + lr) * lda + ktA * 32 + kq;
      d[rf][0] = ldf(Ah + ao);
      d[rf][1] = ldf(Al + ao);
    }
  };
  auto compute = [&](bf16x8 (&a)[2][2], int buf, f32x4 (&an)[2][4]) {
#pragma unroll
    for (int g = 0; g < 3; ++g)
#pragma unroll
      for (int ntl = 0; ntl < 4; ++ntl) {
        int tl2 = (g * 4 + ntl) * 2;
        bf16x8 bh  = *(const bf16x8*)(&Bl[buf][tl2][l * 8]);
        bf16x8 blo = *(const bf16x8*)(&Bl[buf][tl2 + 1][l * 8]);
#pragma unroll
        for (int rf = 0; rf < 2; ++rf) {
          if (g < 2)
            arz[rf][g][ntl] = mf(a[rf][0], blo, mf(a[rf][1], bh,
                                 mf(a[rf][0], bh, arz[rf][g][ntl])));
          else
            an[rf][ntl] = mf(a[rf][0], blo, mf(a[rf][1], bh,
                             mf(a[rf][0], bh, an[rf][ntl])));
        }
      }
  };
  auto acopy = [&](bf16x8 (&dst)[2][2], bf16x8 (&src)[2][2]) {
#pragma unroll
    for (int rf = 0; rf < 2; ++rf) {
      dst[rf][0] = src[rf][0];
      dst[rf][1] = src[rf][1];
    }
  };

  bf16x8 w0[6], w1[6], acur[2][2], anx[2][2];

  stage_load(W1h, W1l, 0, w0);
  aload(A1h, A1l, lda1, 0, acur);
  stage_write(w0, 0);
  __syncthreads();

  for (int kt = 0; kt < KT1; ++kt) {
    const int buf = kt & 1;
    const bool more1 = (kt + 1 < KT1);
    const bool next = more1 || (KT2 > 0);
    if (more1)      { stage_load(W1h, W1l, kt + 1, w1); aload(A1h, A1l, lda1, kt + 1, anx); }
    else if (KT2)   { stage_load(W2h, W2l, 0, w1);      aload(HPh, HPl, HH, 0, anx); }
    compute(acur, buf, axn);
    if (next) stage_write(w1, buf ^ 1);
    __syncthreads();
    if (next) acopy(acur, anx);
  }
  if (KT2) {
    for (int kt = 0; kt < 16; ++kt) {
      const int buf = (KT1 + kt) & 1;
      const bool next = (kt + 1 < 16);
      if (next) { stage_load(W2h, W2l, kt + 1, w1); aload(HPh, HPl, HH, kt + 1, anx); }
      compute(acur, buf, ahn);
      if (next) stage_write(w1, buf ^ 1);
      __syncthreads();
      if (next) acopy(acur, anx);
    }
  }

#pragma unroll
  for (int ntl = 0; ntl < 4; ++ntl) {
    const int col = cw + ntl * 16 + lr;
    const float bx0 = b1[col], bx1 = b1[col + HH], bx2 = b1[col + 2 * HH];
    const float bh0 = b2[col], bh1 = b2[col + HH], bh2 = b2[col + 2 * HH];
#pragma unroll
    for (int rf = 0; rf < 2; ++rf)
#pragma unroll
      for (int i = 0; i < 4; ++i) {
        const int row = m0 + rf * 16 + lq * 4 + i;
        const float rr = sigf(arz[rf][0][ntl][i] + bx0 + bh0);
        const float zz = sigf(arz[rf][1][ntl][i] + bx1 + bh1);
        const float nn = tanhf(axn[rf][ntl][i] + bx2 + rr * (ahn[rf][ntl][i] + bh2));
        float hp = 0.f;
        const size_t hidx = (size_t)row * HH + col;
        if (!zero_h)
          hp = __bfloat162float(HPh[hidx]) + __bfloat162float(HPl[hidx]);
        const float hn = (1.f - zz) * nn + zz * hp;
        bf16 sh, sl;
        split2(hn, sh, sl);
        HOh[hidx] = sh;
        HOl[hidx] = sl;
      }
  }
}

// ---------------------------------------------------------------------------
// gru2n (small-C ramp path): the proven R1/v3 128x32 kernel, verbatim.
// Fills the chip at C>=4 with a cheaper serial staging chain than v7
// (12 KiB vs 24 KiB per kt). Output is bitwise-identical to gru2, so the
// host may mix the two freely per phase.
// ---------------------------------------------------------------------------
template <int KT1>
__global__ __launch_bounds__(256) void gru2n(
    const bf16* __restrict__ a1h, const bf16* __restrict__ a1l, int lda1,
    const bf16* __restrict__ W1h, const bf16* __restrict__ W1l,
    const float* __restrict__ b1,
    const bf16* __restrict__ hbh, const bf16* __restrict__ hbl,
    const bf16* __restrict__ W2h, const bf16* __restrict__ W2l,
    const float* __restrict__ b2,
    bf16* __restrict__ obh, bf16* __restrict__ obl,
    GruPhase ph)
{
  __shared__ __align__(16) __bf16 Bl[2][12][512];
  const int tid = threadIdx.x;
  const int w = tid >> 6, l = tid & 63;
  const int lr = l & 15, lq = l >> 4, kq = lq * 8;
  const int cell = blockIdx.y >> 3, rt = blockIdx.y & 7;
  const int cw = blockIdx.x * 32;
  const int m0 = rt * 128 + w * 32;
  const bf16* A1h = a1h + ph.a1off[cell];
  const bf16* A1l = a1l + ph.a1off[cell];
  const bf16* HPh = hbh + ph.hoff[cell];
  const bf16* HPl = hbl + ph.hoff[cell];
  bf16* HOh = obh + ph.ooff[cell];
  bf16* HOl = obl + ph.ooff[cell];
  const int zero_h = (ph.zmask >> cell) & 1;
  const int KT2 = zero_h ? 0 : 16;

  const f32x4 vzero = {0.f, 0.f, 0.f, 0.f};
  f32x4 arz[2][2][2];
  f32x4 axn[2][2], ahn[2][2];
#pragma unroll
  for (int rf = 0; rf < 2; ++rf)
#pragma unroll
    for (int ntl = 0; ntl < 2; ++ntl) {
      arz[rf][0][ntl] = vzero; arz[rf][1][ntl] = vzero;
      axn[rf][ntl] = vzero; ahn[rf][ntl] = vzero;
    }

  int tl2a[3], uia[3], hlr[3];
  size_t soff[3];
#pragma unroll
  for (int r = 0; r < 3; ++r) {
    int u = r * 256 + tid;
    int tl2 = u >> 6;
    int ui = u & 63;
    int hl = tl2 & 1;
    int gn = tl2 >> 1;
    int g = gn >> 1, ntl = gn & 1;
    int ntg = g * 32 + (cw >> 4) + ntl;
    tl2a[r] = tl2; uia[r] = ui; hlr[r] = hl;
    soff[r] = ((size_t)ntg * 64 + ui) * 8;
  }

  auto stage_load = [&](const bf16* Wh, const bf16* Wl2, int ktW,
                        bf16x8 (&v)[3]) {
#pragma unroll
    for (int r = 0; r < 3; ++r)
      v[r] = ldf((hlr[r] ? Wl2 : Wh) + soff[r] + (size_t)ktW * (NT * 512));
  };
  auto stage_write = [&](bf16x8 (&v)[3], int buf) {
#pragma unroll
    for (int r = 0; r < 3; ++r)
      *(bf16x8*)(&Bl[buf][tl2a[r]][uia[r] * 8]) = v[r];
  };
  auto aload = [&](const bf16* Ah, const bf16* Al, int lda, int ktA,
                   bf16x8 (&d)[2][2]) {
#pragma unroll
    for (int rf = 0; rf < 2; ++rf) {
      const size_t ao = (size_t)(m0 + rf * 16 + lr) * lda + ktA * 32 + kq;
      d[rf][0] = ldf(Ah + ao);
      d[rf][1] = ldf(Al + ao);
    }
  };
  auto compute = [&](bf16x8 (&a)[2][2], int buf, f32x4 (&an)[2][2]) {
#pragma unroll
    for (int g = 0; g < 3; ++g)
#pragma unroll
      for (int ntl = 0; ntl < 2; ++ntl) {
        int tl2 = (g * 2 + ntl) * 2;
        bf16x8 bh  = *(const bf16x8*)(&Bl[buf][tl2][l * 8]);
        bf16x8 blo = *(const bf16x8*)(&Bl[buf][tl2 + 1][l * 8]);
#pragma unroll
        for (int rf = 0; rf < 2; ++rf) {
          if (g < 2)
            arz[rf][g][ntl] = mf(a[rf][0], blo, mf(a[rf][1], bh,
                                 mf(a[rf][0], bh, arz[rf][g][ntl])));
          else
            an[rf][ntl] = mf(a[rf][0], blo, mf(a[rf][1], bh,
                             mf(a[rf][0], bh, an[rf][ntl])));
        }
      }
  };
  auto acopy = [&](bf16x8 (&dst)[2][2], bf16x8 (&src)[2][2]) {
#pragma unroll
    for (int rf = 0; rf < 2; ++rf) {
      dst[rf][0] = src[rf][0];
      dst[rf][1] = src[rf][1];
    }
  };

  bf16x8 w0[3], w1[3], acur[2][2], anx[2][2];

  stage_load(W1h, W1l, 0, w0);
  aload(A1h, A1l, lda1, 0, acur);
  stage_write(w0, 0);
  __syncthreads();

  for (int kt = 0; kt < KT1; ++kt) {
    const int buf = kt & 1;
    const bool more1 = (kt + 1 < KT1);
    const bool next = more1 || (KT2 > 0);
    if (more1)      { stage_load(W1h, W1l, kt + 1, w1); aload(A1h, A1l, lda1, kt + 1, anx); }
    else if (KT2)   { stage_load(W2h, W2l, 0, w1);      aload(HPh, HPl, HH, 0, anx); }
    compute(acur, buf, axn);
    if (next) stage_write(w1, buf ^ 1);
    __syncthreads();
    if (next) acopy(acur, anx);
  }
  if (KT2) {
    for (int kt = 0; kt < 16; ++kt) {
      const int buf = (KT1 + kt) & 1;
      const bool next = (kt + 1 < 16);
      if (next) { stage_load(W2h, W2l, kt + 1, w1); aload(HPh, HPl, HH, kt + 1, anx); }
      compute(acur, buf, ahn);
      if (next) stage_write(w1, buf ^ 1);
      __syncthreads();
      if (next) acopy(acur, anx);
    }
  }

#pragma unroll
  for (int ntl = 0; ntl < 2; ++ntl) {
    const int col = cw + ntl * 16 + lr;
    const float bx0 = b1[col], bx1 = b1[col + HH], bx2 = b1[col + 2 * HH];
    const float bh0 = b2[col], bh1 = b2[col + HH], bh2 = b2[col + 2 * HH];
#pragma unroll
    for (int rf = 0; rf < 2; ++rf)
#pragma unroll
      for (int i = 0; i < 4; ++i) {
        const int row = m0 + rf * 16 + lq * 4 + i;
        const float rr = sigf(arz[rf][0][ntl][i] + bx0 + bh0);
        const float zz = sigf(arz[rf][1][ntl][i] + bx1 + bh1);
        const float nn = tanhf(axn[rf][ntl][i] + bx2 + rr * (ahn[rf][ntl][i] + bh2));
        float hp = 0.f;
        const size_t hidx = (size_t)row * HH + col;
        if (!zero_h)
          hp = __bfloat162float(HPh[hidx]) + __bfloat162float(HPl[hidx]);
        const float hn = (1.f - zz) * nn + zz * hp;
        bf16 sh, sl;
        split2(hn, sh, sl);
        HOh[hidx] = sh;
        HOl[hidx] = sl;
      }
  }
}

// ---------------------------------------------------------------------------
// Output projection v2 (MFMA): o = relu(h1) @ W_out^T + b_out + res.
// Replaces the VALU out_v (192 VMEM instrs/thread, ~40-60us) with the same
// 3-term split-bf16 MFMA used in gru2. W_out pre-swizzled into frag order
// (NTO=12 tiles); B-frags read straight from global (L2-resident, 393 KB).
// Block = 128 rows x 64 cols (4 waves, each 32x64); grid (3, 8) = 24 blocks.
// ---------------------------------------------------------------------------
__global__ __launch_bounds__(256) void out_m(
    const bf16* __restrict__ h1h, const bf16* __restrict__ h1l,
    const bf16* __restrict__ Wh, const bf16* __restrict__ Wl,
    const float* __restrict__ bo,
    float* __restrict__ res,
    bf16* __restrict__ yh, bf16* __restrict__ yl,
    float* __restrict__ outp, int d)
{
  const int tid = threadIdx.x;
  const int w = tid >> 6, l = tid & 63;
  const int lr = l & 15, lq = l >> 4, kq = lq * 8;
  const int m0 = blockIdx.y * 128 + w * 32;
  const int cw = blockIdx.x * 64;

  const f32x4 vzero = {0.f, 0.f, 0.f, 0.f};
  f32x4 acc[2][4];
#pragma unroll
  for (int rf = 0; rf < 2; ++rf)
#pragma unroll
    for (int ntl = 0; ntl < 4; ++ntl) acc[rf][ntl] = vzero;

  for (int kt = 0; kt < HH / 32; ++kt) {
    // A-frags: relu(hi+lo) re-split to bf16 hi/lo (RNE, same as split2)
    bf16x8 ah[2], al[2];
#pragma unroll
    for (int rf = 0; rf < 2; ++rf) {
      const size_t ao = (size_t)(m0 + rf * 16 + lr) * HH + kt * 32 + kq;
      bf16x8 hh = ldf(h1h + ao);
      bf16x8 hl = ldf(h1l + ao);
#pragma unroll
      for (int j = 0; j < 8; ++j) {
        float v = fmaxf((float)hh[j] + (float)hl[j], 0.f);
        __bf16 vh = (__bf16)v;
        __bf16 vl = (__bf16)(v - (float)vh);
        ah[rf][j] = vh;
        al[rf][j] = vl;
      }
    }
#pragma unroll
    for (int ntl = 0; ntl < 4; ++ntl) {
      const int nt = (cw >> 4) + ntl;
      const size_t bo_ = ((size_t)(kt * NTO + nt) * 64 + l) * 8;
      bf16x8 bh = ldf(Wh + bo_);
      bf16x8 bl = ldf(Wl + bo_);
#pragma unroll
      for (int rf = 0; rf < 2; ++rf)
        acc[rf][ntl] = mf(ah[rf], bl, mf(al[rf], bh,
                          mf(ah[rf], bh, acc[rf][ntl])));
    }
  }

#pragma unroll
  for (int ntl = 0; ntl < 4; ++ntl) {
    const int col = cw + ntl * 16 + lr;
    if (col >= YY) continue;           // padded cols 188..191: no writes
    const float bc = bo[col];
#pragma unroll
    for (int rf = 0; rf < 2; ++rf)
#pragma unroll
      for (int i = 0; i < 4; ++i) {
        const int row = m0 + rf * 16 + lq * 4 + i;
        const int ridx = row * YY + col;
        float o = acc[rf][ntl][i] + bc + res[ridx];
        res[ridx] = o;
        outp[((size_t)row * DS + d) * YY + col] = o;
        bf16 sh, sl;
        split2(o, sh, sl);
        yh[(size_t)row * YP + col] = sh;
        yl[(size_t)row * YP + col] = sl;
      }
  }
}

extern "C" void kernel_launch(void* const* d_in, const int* in_sizes, int n_in,
                              void* d_out, int out_size, void* d_ws, size_t ws_size,
                              hipStream_t stream)
{
  // role mapping insurance (dict-order signature, greedy fallback)
  static const int sig_dict[11] = {2501632, 288768, 786432, 1536, 1536,
                                   786432, 786432, 1536, 1536, 96256, 188};
  int map[11];
  bool dict_ok = (n_in == 11);
  if (dict_ok)
    for (int r = 0; r < 11; ++r)
      if (in_sizes[r] != sig_dict[r]) { dict_ok = false; break; }
  if (dict_ok) { for (int r = 0; r < 11; ++r) map[r] = r; }
  else {
    bool used[16] = {};
    for (int r = 0; r < 11; ++r) {
      map[r] = r < n_in ? r : 0;
      for (int i = 0; i < n_in && i < 16; ++i)
        if (!used[i] && in_sizes[i] == sig_dict[r]) { map[r] = i; used[i] = true; break; }
    }
  }
  const float* x     = (const float*)d_in[map[0]];
  const float* W_ih0 = (const float*)d_in[map[1]];
  const float* W_hh0 = (const float*)d_in[map[2]];
  const float* b_ih0 = (const float*)d_in[map[3]];
  const float* b_hh0 = (const float*)d_in[map[4]];
  const float* W_ih1 = (const float*)d_in[map[5]];
  const float* W_hh1 = (const float*)d_in[map[6]];
  const float* b_ih1 = (const float*)d_in[map[7]];
  const float* b_hh1 = (const float*)d_in[map[8]];
  const float* W_out = (const float*)d_in[map[9]];
  const float* b_out = (const float*)d_in[map[10]];
  float* outp = (float*)d_out;

  const int S    = (ws_size >= (size_t)160 << 20) ? 13 : 7;
  const int SKEW = (S == 13) ? 1 : 2;
  const int NPH  = 12 * SKEW + 13;

  char* p = (char*)d_ws;
  auto alloc = [&](size_t bytes) { char* q = p; p += (bytes + 255) & ~(size_t)255; return q; };
  bf16* tokh = (bf16*)alloc((size_t)26 * BB * YP * 2);
  bf16* tokl = (bf16*)alloc((size_t)26 * BB * YP * 2);
  bf16* W0h  = (bf16*)alloc((size_t)GG * YP * 2);
  bf16* W0l  = (bf16*)alloc((size_t)GG * YP * 2);
  bf16* Wh0h = (bf16*)alloc((size_t)GG * HH * 2);
  bf16* Wh0l = (bf16*)alloc((size_t)GG * HH * 2);
  bf16* Wi1h = (bf16*)alloc((size_t)GG * HH * 2);
  bf16* Wi1l = (bf16*)alloc((size_t)GG * HH * 2);
  bf16* Wh1h = (bf16*)alloc((size_t)GG * HH * 2);
  bf16* Wh1l = (bf16*)alloc((size_t)GG * HH * 2);
  bf16* Woh  = (bf16*)alloc((size_t)YP * HH * 2);   // swizzled W_out frags
  bf16* Wol  = (bf16*)alloc((size_t)YP * HH * 2);
  bf16* h0h = (bf16*)alloc((size_t)2 * S * BB * HH * 2);  // parity x slot
  bf16* h0l = (bf16*)alloc((size_t)2 * S * BB * HH * 2);
  bf16* h1h = (bf16*)alloc((size_t)2 * S * BB * HH * 2);
  bf16* h1l = (bf16*)alloc((size_t)2 * S * BB * HH * 2);
  float* res = (float*)alloc((size_t)BB * YY * 4);

  k_setup<<<(26 * BB * YP + 255) / 256, 256, 0, stream>>>(x, tokh, tokl, res);
  k_swz2<<<NT * (YP / 32) * 64 / 256, 256, 0, stream>>>(W_ih0, W0h, W0l, GG, YY, NT);
  k_swz2<<<NT * (HH / 32) * 64 / 256, 256, 0, stream>>>(W_hh0, Wh0h, Wh0l, GG, HH, NT);
  k_swz2<<<NT * (HH / 32) * 64 / 256, 256, 0, stream>>>(W_ih1, Wi1h, Wi1l, GG, HH, NT);
  k_swz2<<<NT * (HH / 32) * 64 / 256, 256, 0, stream>>>(W_hh1, Wh1h, Wh1l, GG, HH, NT);
  k_swz2<<<NTO * (HH / 32) * 64 / 256, 256, 0, stream>>>(W_out, Woh, Wol, YY, HH, NTO);

  // Diagonal wavefront: phase(d,t) = t + SKEW*d. Cells in phase p read
  // h-parity (p-1)&1, write p&1; slot = d % S.
  for (int phs = 0; phs < NPH; ++phs) {
    GruPhase P0{}, P1{};
    const int pprev = (phs + 1) & 1, pcur = phs & 1;
    int C = 0;
    for (int d = 0; d < DS; ++d) {
      int t = phs - SKEW * d;
      if (t < 0 || t > 12) continue;
      int c = C++;
      P0.a1off[c] = (unsigned)((d + t) * BB * YP);          // token slot d+t
      P0.hoff[c]  = (unsigned)((pprev * S + d % S) * BB * HH);
      P0.ooff[c]  = (unsigned)((pcur * S + d % S) * BB * HH);
      if (t == 0) P0.zmask |= 1 << c;
      P1.a1off[c] = P0.ooff[c];   // L1 input = L0 output of this phase
      P1.hoff[c]  = P0.hoff[c];
      P1.ooff[c]  = P0.ooff[c];
    }
    P0.ncells = P1.ncells = C;
    P1.zmask = P0.zmask;
    if (C <= 4) {
      // ramp phases: 128x32 kernel fills the chip earlier, cheaper serial chain
      const dim3 grid(16, C * 8);
      gru2n<YP / 32><<<grid, 256, 0, stream>>>(tokh, tokl, YP, W0h, W0l, b_ih0,
                                               h0h, h0l, Wh0h, Wh0l, b_hh0,
                                               h0h, h0l, P0);
      gru2n<HH / 32><<<grid, 256, 0, stream>>>(h0h, h0l, HH, Wi1h, Wi1l, b_ih1,
                                               h1h, h1l, Wh1h, Wh1l, b_hh1,
                                               h1h, h1l, P1);
    } else {
      const dim3 grid(8, C * 8);   // x=8 colgroups (one per XCD), y=row-tiles
      gru2<YP / 32><<<grid, 256, 0, stream>>>(tokh, tokl, YP, W0h, W0l, b_ih0,
                                              h0h, h0l, Wh0h, Wh0l, b_hh0,
                                              h0h, h0l, P0);
      gru2<HH / 32><<<grid, 256, 0, stream>>>(h0h, h0l, HH, Wi1h, Wi1l, b_ih1,
                                              h1h, h1l, Wh1h, Wh1l, b_hh1,
                                              h1h, h1l, P1);
    }
    // decode step d finishes at phase 12 + SKEW*d: project + feed token 13+d
    if (phs >= 12 && (phs - 12) % SKEW == 0) {
      const int d = (phs - 12) / SKEW;
      const size_t hoff = (size_t)(pcur * S + d % S) * BB * HH;
      out_m<<<dim3(3, 8), 256, 0, stream>>>(
          h1h + hoff, h1l + hoff, Woh, Wol, b_out, res,
          tokh + (size_t)(13 + d) * BB * YP, tokl + (size_t)(13 + d) * BB * YP,
          outp, d);
    }
  }
}